// Round 4
// baseline (273.432 us; speedup 1.0000x reference)
//
#include <hip/hip_runtime.h>
#include <hip/hip_bf16.h>
#include <cstdint>
#include <cstddef>

// Problem constants
constexpr int T_Q   = 32400;   // BEV queries
constexpr int T_PAD = 32512;   // padded (multiple of 64)
constexpr int S_K   = 16896;   // feature keys
constexpr int E_DIM = 256;
constexpr int HID   = 512;

typedef __bf16 bf16x8 __attribute__((ext_vector_type(8)));
typedef float  f32x4  __attribute__((ext_vector_type(4)));
typedef unsigned short ushort8v __attribute__((ext_vector_type(8)));

__device__ __forceinline__ void async16(const __hip_bfloat16* gp, __hip_bfloat16* lp) {
    __builtin_amdgcn_global_load_lds(
        (const __attribute__((address_space(1))) void*)(gp),
        (__attribute__((address_space(3))) void*)(lp), 16, 0, 0);
}

__device__ __forceinline__ float b2f(unsigned short u) {
    return __uint_as_float(((unsigned)u) << 16);
}

// ---------------------------------------------------------------------------
// prep: v cast into kv cols 256..511 + weight transpose to [N][K] bf16.
constexpr int NB_K = (S_K * E_DIM / 4) / 256;     // 4224
constexpr int NB_PREP = NB_K + 128;

__global__ __launch_bounds__(256) void prep(
    const float* __restrict__ val_in,
    const float* __restrict__ s0, const float* __restrict__ s1,
    const float* __restrict__ s2, const float* __restrict__ s3,
    __hip_bfloat16* __restrict__ kvB,
    __hip_bfloat16* __restrict__ d0, __hip_bfloat16* __restrict__ d1,
    __hip_bfloat16* __restrict__ d2, __hip_bfloat16* __restrict__ d3) {
    __shared__ float tb[64][65];
    const int b = blockIdx.x;
    const int tid = threadIdx.x;

    if (b < NB_K) {
        int i = (b * 256 + tid) * 4;
        float4 f = *(const float4*)(val_in + i);
        union { ushort4 u4; __hip_bfloat16 bb[4]; } cv;
        cv.bb[0] = __float2bfloat16(f.x);
        cv.bb[1] = __float2bfloat16(f.y);
        cv.bb[2] = __float2bfloat16(f.z);
        cv.bb[3] = __float2bfloat16(f.w);
        int r = i >> 8, c = i & 255;   // v goes to kv[r][256+c]
        *(ushort4*)(kvB + (size_t)r * 512 + 256 + c) = cv.u4;
        return;
    }

    // transpose: matrix m (0:q_w1 K256 N512, 1:q_w2 K512 N256, 2:k_w1, 3:k_w2)
    int tloc = b - NB_K;
    int m = tloc >> 5;
    int tt = tloc & 31;
    const float* S = m == 0 ? s0 : m == 1 ? s1 : m == 2 ? s2 : s3;
    __hip_bfloat16* D = m == 0 ? d0 : m == 1 ? d1 : m == 2 ? d2 : d3;
    int Kd, Nd, kt, nt;
    if ((m & 1) == 0) { Kd = 256; Nd = 512; kt = tt & 3; nt = tt >> 2; }
    else              { Kd = 512; Nd = 256; kt = tt & 7; nt = tt >> 3; }
    int tx = tid & 63, ty = tid >> 6;
#pragma unroll
    for (int p = 0; p < 16; ++p) {
        int row = ty * 16 + p;
        tb[row][tx] = S[(size_t)(kt * 64 + row) * Nd + nt * 64 + tx];
    }
    __syncthreads();
#pragma unroll
    for (int p = 0; p < 16; ++p) {
        int row = ty * 16 + p;
        D[(size_t)(nt * 64 + row) * Kd + kt * 64 + tx] = __float2bfloat16(tb[tx][row]);
    }
}

// ---------------------------------------------------------------------------
// Fused MLP v4: one block owns 64 rows end-to-end; 2 blocks/CU via 72 KB LDS.
//   out = sum_nh relu(A @ W1[:,nh*256:+256] + b1) @ W2[nh*256:+256,:]
//   Per nh half: phase 1 (4 stages) computes hid half into Hs (32 KB);
//   phase 2 (4 stages) accumulates acc2 += Hs @ W2-half.
//   A is staged per-stage as 64x64 fp32->bf16 slabs (A read twice; BW is idle).
//   Sync structure per stage is EXACTLY the R2-proven template:
//     {ds_write Aslab / issue Bs DMA; __syncthreads(); compute; __syncthreads();}
//   -> every buffer overwrite is separated from its last read by a drained
//      barrier. No cross-stage DMA pipelining (the R3 race is removed);
//   overlap comes from 2 co-resident blocks/CU (16 waves) instead.

constexpr int MLP_QT = T_PAD / 64;        // 508
constexpr int MLP_KT = S_K / 64;          // 264
constexpr int MLP_NB = MLP_QT + MLP_KT;   // 772

__global__ __launch_bounds__(512, 4) void mlp_fused(
    const float* __restrict__ Aq, const float* __restrict__ Ak,
    const __hip_bfloat16* __restrict__ W1q, const __hip_bfloat16* __restrict__ W1k,
    const __hip_bfloat16* __restrict__ W2q, const __hip_bfloat16* __restrict__ W2k,
    const float* __restrict__ b1q, const float* __restrict__ b1k,
    const float* __restrict__ b2q, const float* __restrict__ b2k,
    __hip_bfloat16* __restrict__ Cq, __hip_bfloat16* __restrict__ Ck,
    float scaleq, int qtiles) {
    __shared__ __align__(16) __hip_bfloat16 Aslab[64 * 64];    //  8 KB
    __shared__ __align__(16) __hip_bfloat16 Bs[256 * 64];      // 32 KB
    __shared__ __align__(16) __hip_bfloat16 Hs[64 * 256];      // 32 KB

    const int b = blockIdx.x;
    const bool isq = b < qtiles;
    const float* A  = isq ? Aq : Ak;
    const __hip_bfloat16* W1 = isq ? W1q : W1k;
    const __hip_bfloat16* W2 = isq ? W2q : W2k;
    const float* b1 = isq ? b1q : b1k;
    const float* b2 = isq ? b2q : b2k;
    __hip_bfloat16* C = isq ? Cq : Ck;
    const int ldc = isq ? E_DIM : 512;
    const float scale = isq ? scaleq : 1.0f;
    const int mrow0 = (isq ? b : b - qtiles) * 64;
    const int rowlim = isq ? T_Q : S_K;

    const int tid = threadIdx.x;
    const int w = tid >> 6, l = tid & 63;
    const int lm = l & 15, lq = l >> 4;
    const int wm = w >> 2;                    // M-half: rows wm*32..wm*32+31
    const int wn4 = w & 3;                    // N-quarter: cols wn4*64..+63
    const int srow8 = l >> 3;                 // 0..7
    const int u8 = l & 7;
    const int pu8 = u8 ^ srow8;               // phys unit for Aslab write
    const int scolB = (u8 ^ srow8) << 3;      // swizzled source col for B DMA

    f32x4 acc2[2][4] = {};

#pragma unroll 1
    for (int nh = 0; nh < 2; ++nh) {
        // ---- phase 1: hidHalf = relu(A @ W1[:, nh*256:+256] + b1half) ----
        f32x4 acc[2][4] = {};
#pragma unroll 1
        for (int st = 0; st < 4; ++st) {
            const int k0 = st * 64;
            // A slab: 64 rows x 64 k, fp32 -> bf16, swizzled ds_write
            {
                int r = w * 8 + srow8;        // 0..63
                int gr = mrow0 + r;
                float4 f0 = make_float4(0.f, 0.f, 0.f, 0.f);
                float4 f1 = make_float4(0.f, 0.f, 0.f, 0.f);
                if (gr < rowlim) {
                    const float* ap = A + (size_t)gr * 256 + k0 + u8 * 8;
                    f0 = *(const float4*)ap;
                    f1 = *(const float4*)(ap + 4);
                }
                union { bf16x8 v; __hip_bfloat16 bb[8]; } cv;
                cv.bb[0] = __float2bfloat16(f0.x); cv.bb[1] = __float2bfloat16(f0.y);
                cv.bb[2] = __float2bfloat16(f0.z); cv.bb[3] = __float2bfloat16(f0.w);
                cv.bb[4] = __float2bfloat16(f1.x); cv.bb[5] = __float2bfloat16(f1.y);
                cv.bb[6] = __float2bfloat16(f1.z); cv.bb[7] = __float2bfloat16(f1.w);
                *(bf16x8*)(Aslab + r * 64 + pu8 * 8) = cv.v;
            }
            // B slab: W1 rows nh*256 .. +255, k cols k0..k0+63
#pragma unroll
            for (int c = 0; c < 4; ++c) {
                int r = w * 32 + c * 8 + srow8;
                async16(W1 + (size_t)(nh * 256 + r) * 256 + k0 + scolB,
                        Bs + (w * 32 + c * 8) * 64);
            }
            __syncthreads();
#pragma unroll
            for (int ks = 0; ks < 2; ++ks) {
                bf16x8 af[2], bfr[4];
#pragma unroll
                for (int mi = 0; mi < 2; ++mi) {
                    int row = wm * 32 + mi * 16 + lm;
                    int pu = (ks * 4 + lq) ^ (row & 7);
                    af[mi] = *(const bf16x8*)(Aslab + row * 64 + pu * 8);
                }
#pragma unroll
                for (int ni = 0; ni < 4; ++ni) {
                    int brow = wn4 * 64 + ni * 16 + lm;
                    int pu = (ks * 4 + lq) ^ (brow & 7);
                    bfr[ni] = *(const bf16x8*)(Bs + brow * 64 + pu * 8);
                }
#pragma unroll
                for (int mi = 0; mi < 2; ++mi)
#pragma unroll
                    for (int ni = 0; ni < 4; ++ni)
                        acc[mi][ni] = __builtin_amdgcn_mfma_f32_16x16x32_bf16(
                            af[mi], bfr[ni], acc[mi][ni], 0, 0, 0);
            }
            __syncthreads();
        }

        // phase-1 epilogue: bias + relu + cvt -> Hs (64x256, swizzled)
#pragma unroll
        for (int ni = 0; ni < 4; ++ni) {
            int col = wn4 * 64 + ni * 16 + lm;          // local 0..255
            float bv = b1[nh * 256 + col];
            int un = col >> 3, el = col & 7;            // un 0..31
#pragma unroll
            for (int mi = 0; mi < 2; ++mi) {
#pragma unroll
                for (int r = 0; r < 4; ++r) {
                    int row = wm * 32 + mi * 16 + lq * 4 + r;
                    float vv = fmaxf(acc[mi][ni][r] + bv, 0.f);
                    int pu = (un & 24) | ((un & 7) ^ (row & 7));
                    Hs[row * 256 + pu * 8 + el] = __float2bfloat16(vv);
                }
            }
        }

        // ---- phase 2 partial: acc2 += hidHalf @ W2[nh*256:+256, :] ----
#pragma unroll 1
        for (int st = 0; st < 4; ++st) {
            const int k0 = st * 64;
#pragma unroll
            for (int c = 0; c < 4; ++c) {
                int r = w * 32 + c * 8 + srow8;         // out col 0..255
                async16(W2 + (size_t)r * 512 + nh * 256 + k0 + scolB,
                        Bs + (w * 32 + c * 8) * 64);
            }
            __syncthreads();     // drains Hs ds_writes (st==0) + Bs DMA
#pragma unroll
            for (int ks = 0; ks < 2; ++ks) {
                bf16x8 af[2], bfr[4];
#pragma unroll
                for (int mi = 0; mi < 2; ++mi) {
                    int row = wm * 32 + mi * 16 + lm;
                    int un = st * 8 + ks * 4 + lq;      // 0..31
                    int pu = (un & 24) | ((un & 7) ^ (row & 7));
                    af[mi] = *(const bf16x8*)(Hs + row * 256 + pu * 8);
                }
#pragma unroll
                for (int ni = 0; ni < 4; ++ni) {
                    int brow = wn4 * 64 + ni * 16 + lm;
                    int pu = (ks * 4 + lq) ^ (brow & 7);
                    bfr[ni] = *(const bf16x8*)(Bs + brow * 64 + pu * 8);
                }
#pragma unroll
                for (int mi = 0; mi < 2; ++mi)
#pragma unroll
                    for (int ni = 0; ni < 4; ++ni)
                        acc2[mi][ni] = __builtin_amdgcn_mfma_f32_16x16x32_bf16(
                            af[mi], bfr[ni], acc2[mi][ni], 0, 0, 0);
            }
            __syncthreads();
        }
    }

    // final epilogue
#pragma unroll
    for (int ni = 0; ni < 4; ++ni) {
        int col = wn4 * 64 + ni * 16 + lm;
        float bv = b2[col];
#pragma unroll
        for (int mi = 0; mi < 2; ++mi) {
            size_t rowb = (size_t)mrow0 + wm * 32 + mi * 16 + lq * 4;
#pragma unroll
            for (int r = 0; r < 4; ++r) {
                float vv = (acc2[mi][ni][r] + bv) * scale;
                C[(rowb + r) * ldc + col] = __float2bfloat16(vv);
            }
        }
    }
}

// ---------------------------------------------------------------------------
// Attention: one wave per query, TWO points per step (one per half-wave).
// 4 pair-buffers deep register prefetch (8 points lookahead).
// Defer-max skips the rescale when no head's pair-max beats the running max.
// Persistent grid: 2026 blocks fully resident.

#define PREFP(KB, VB, C)                                                     \
    {                                                                        \
        int f_ = __shfl(myf, (C) + half);                                    \
        const __hip_bfloat16* p_ = kv + ((size_t)f_ << 9) + (sub << 3);      \
        KB = *(const ushort8v*)p_;                                           \
        VB = *(const ushort8v*)(p_ + 256);                                   \
    }

#define PROCP(KB, VB, C)                                                     \
    {                                                                        \
        float wv = 0.f;                                                      \
        _Pragma("unroll") for (int i = 0; i < 8; ++i)                        \
            wv = fmaf(qf[i], b2f(KB[i]), wv);                                \
        wv += __shfl_xor(wv, 1);                                             \
        wv += __shfl_xor(wv, 2);                                             \
        float sc = ((C) + half < L) ? wv : -1e30f;                           \
        float so = __shfl_xor(sc, 32);                                       \
        float pm = fmaxf(sc, so);                                            \
        if (__all(pm <= m)) {                                                \
            float p = __expf(sc - m);                                        \
            s += p;                                                          \
            _Pragma("unroll") for (int i = 0; i < 8; ++i)                    \
                a[i] = fmaf(p, b2f(VB[i]), a[i]);                            \
        } else {                                                             \
            float mn = fmaxf(m, pm);                                         \
            float al = __expf(m - mn);                                       \
            float p  = __expf(sc - mn);                                      \
            m = mn;                                                          \
            s = fmaf(s, al, p);                                              \
            _Pragma("unroll") for (int i = 0; i < 8; ++i)                    \
                a[i] = fmaf(p, b2f(VB[i]), a[i] * al);                       \
        }                                                                    \
    }

#define STEPP(KB, VB, J)                                                     \
    if (c + (J) < L) {                                                       \
        PROCP(KB, VB, c + (J));                                              \
        if (c + (J) + 8 < L) PREFP(KB, VB, c + (J) + 8);                     \
    }

constexpr int ATTN_BLOCKS = 2026;   // fully resident

__global__ __launch_bounds__(256) void attn_kernel(
    const __hip_bfloat16* __restrict__ q,
    const __hip_bfloat16* __restrict__ kv,
    const int* __restrict__ rf,
    const int* __restrict__ starts,
    const int* __restrict__ lens,
    float* __restrict__ out) {
    const int wid = threadIdx.x >> 6;
    const int l = threadIdx.x & 63;
    const int sub = l & 31, half = l >> 5;
    const int tstride = gridDim.x * 4;

    for (int t = blockIdx.x * 4 + wid; t < T_Q; t += tstride) {
        int su = __builtin_amdgcn_readfirstlane(starts[t]);
        int L  = __builtin_amdgcn_readfirstlane(lens[t]);

        int li = l < L - 1 ? l : L - 1;   // clamp so any shfl source is valid
        int myf = rf[su + li];

        ushort8v qu = *(const ushort8v*)(q + (size_t)t * 256 + sub * 8);
        float qf[8];
#pragma unroll
        for (int i = 0; i < 8; ++i) qf[i] = b2f(qu[i]);

        float m = -INFINITY, s = 0.f;
        float a[8] = {0.f, 0.f, 0.f, 0.f, 0.f, 0.f, 0.f, 0.f};

        ushort8v k0 = {}, v0 = {}, k1 = {}, v1 = {};
        ushort8v k2 = {}, v2 = {}, k3 = {}, v3 = {};
        PREFP(k0, v0, 0);
        if (L > 2) PREFP(k1, v1, 2);
        if (L > 4) PREFP(k2, v2, 4);
        if (L > 6) PREFP(k3, v3, 6);

        for (int c = 0; c < L; c += 8) {
            STEPP(k0, v0, 0)
            STEPP(k1, v1, 2)
            STEPP(k2, v2, 4)
            STEPP(k3, v3, 6)
        }

        // merge half-wave partials (both halves end with identical m)
        float st = s + __shfl_xor(s, 32);
#pragma unroll
        for (int i = 0; i < 8; ++i) a[i] += __shfl_xor(a[i], 32);

        // v-half lanes write: lane 32+x owns out dims x*8..x*8+7
        if (half) {
            float inv = 1.f / st;
            float* op = out + (size_t)t * 256 + sub * 8;
            float4 o0, o1;
            o0.x = a[0] * inv; o0.y = a[1] * inv; o0.z = a[2] * inv; o0.w = a[3] * inv;
            o1.x = a[4] * inv; o1.y = a[5] * inv; o1.z = a[6] * inv; o1.w = a[7] * inv;
            *(float4*)op = o0;
            *(float4*)(op + 4) = o1;
        }
    }
}

// ---------------------------------------------------------------------------
extern "C" void kernel_launch(void* const* d_in, const int* in_sizes, int n_in,
                              void* d_out, int out_size, void* d_ws, size_t ws_size,
                              hipStream_t stream) {
    const float* q_in   = (const float*)d_in[0];
    const float* key_in = (const float*)d_in[1];
    const float* val_in = (const float*)d_in[2];
    const float* q_w1   = (const float*)d_in[3];
    const float* q_b1   = (const float*)d_in[4];
    const float* q_w2   = (const float*)d_in[5];
    const float* q_b2   = (const float*)d_in[6];
    const float* k_w1   = (const float*)d_in[7];
    const float* k_b1   = (const float*)d_in[8];
    const float* k_w2   = (const float*)d_in[9];
    const float* k_b2   = (const float*)d_in[10];
    const int* ranks_feat = (const int*)d_in[11];
    const int* starts     = (const int*)d_in[13];
    const int* lens       = (const int*)d_in[14];
    float* out = (float*)d_out;

    char* ws = (char*)d_ws;
    size_t off = 0;
    auto alloc = [&](size_t bytes) {
        char* p = ws + off;
        off += (bytes + 255) & ~(size_t)255;
        return p;
    };
    __hip_bfloat16* qMl  = (__hip_bfloat16*)alloc((size_t)T_PAD * E_DIM * 2);
    __hip_bfloat16* kvB  = (__hip_bfloat16*)alloc((size_t)S_K * 512 * 2);
    __hip_bfloat16* w1qT = (__hip_bfloat16*)alloc((size_t)HID * E_DIM * 2);
    __hip_bfloat16* w2qT = (__hip_bfloat16*)alloc((size_t)E_DIM * HID * 2);
    __hip_bfloat16* w1kT = (__hip_bfloat16*)alloc((size_t)HID * E_DIM * 2);
    __hip_bfloat16* w2kT = (__hip_bfloat16*)alloc((size_t)E_DIM * HID * 2);
    (void)ws_size; (void)n_in; (void)out_size; (void)in_sizes;

    prep<<<NB_PREP, 256, 0, stream>>>(val_in, q_w1, q_w2, k_w1, k_w2,
                                      kvB, w1qT, w2qT, w1kT, w2kT);

    const float qscale = 0.17677669529663687f;  // 1/sqrt(32)

    mlp_fused<<<MLP_NB, 512, 0, stream>>>(
        q_in, key_in, w1qT, w1kT, w2qT, w2kT,
        q_b1, k_b1, q_b2, k_b2, qMl, kvB, qscale, MLP_QT);

    attn_kernel<<<ATTN_BLOCKS, 256, 0, stream>>>(qMl, kvB, ranks_feat, starts, lens, out);
}

// Round 5
// 264.708 us; speedup vs baseline: 1.0330x; 1.0330x over previous
//
#include <hip/hip_runtime.h>
#include <hip/hip_bf16.h>
#include <cstdint>
#include <cstddef>

// Problem constants
constexpr int T_Q   = 32400;   // BEV queries
constexpr int T_PAD = 32512;   // padded (multiple of 128)
constexpr int S_K   = 16896;   // feature keys
constexpr int E_DIM = 256;
constexpr int HID   = 512;

typedef __bf16 bf16x8 __attribute__((ext_vector_type(8)));
typedef float  f32x4  __attribute__((ext_vector_type(4)));
typedef unsigned short ushort8v __attribute__((ext_vector_type(8)));

__device__ __forceinline__ void async16(const __hip_bfloat16* gp, __hip_bfloat16* lp) {
    __builtin_amdgcn_global_load_lds(
        (const __attribute__((address_space(1))) void*)(gp),
        (__attribute__((address_space(3))) void*)(lp), 16, 0, 0);
}

__device__ __forceinline__ float b2f(unsigned short u) {
    return __uint_as_float(((unsigned)u) << 16);
}

// ---------------------------------------------------------------------------
// prep (weights only now): transpose 4 weight matrices to [N][K] bf16.
// The kv v-cast moved into mlp_fused's k-side blocks (same rows).
__global__ __launch_bounds__(256) void prep(
    const float* __restrict__ s0, const float* __restrict__ s1,
    const float* __restrict__ s2, const float* __restrict__ s3,
    __hip_bfloat16* __restrict__ d0, __hip_bfloat16* __restrict__ d1,
    __hip_bfloat16* __restrict__ d2, __hip_bfloat16* __restrict__ d3) {
    __shared__ float tb[64][65];
    const int b = blockIdx.x;
    const int tid = threadIdx.x;

    // matrix m (0:q_w1 K256 N512, 1:q_w2 K512 N256, 2:k_w1, 3:k_w2)
    int m = b >> 5;
    int tt = b & 31;
    const float* S = m == 0 ? s0 : m == 1 ? s1 : m == 2 ? s2 : s3;
    __hip_bfloat16* D = m == 0 ? d0 : m == 1 ? d1 : m == 2 ? d2 : d3;
    int Kd, Nd, kt, nt;
    if ((m & 1) == 0) { Kd = 256; Nd = 512; kt = tt & 3; nt = tt >> 2; }
    else              { Kd = 512; Nd = 256; kt = tt & 7; nt = tt >> 3; }
    int tx = tid & 63, ty = tid >> 6;
#pragma unroll
    for (int p = 0; p < 16; ++p) {
        int row = ty * 16 + p;
        tb[row][tx] = S[(size_t)(kt * 64 + row) * Nd + nt * 64 + tx];
    }
    __syncthreads();
#pragma unroll
    for (int p = 0; p < 16; ++p) {
        int row = ty * 16 + p;
        D[(size_t)(nt * 64 + row) * Kd + kt * 64 + tx] = __float2bfloat16(tb[tx][row]);
    }
}

// ---------------------------------------------------------------------------
// Fused MLP v5: BM=128 block tile (m93 ladder step: 64x64 per-wave output,
// acc[4][4]), same R4-proven per-stage sync template:
//   { stage A slab (fp32->bf16 ds_write) / issue Bs DMA; __syncthreads();
//     compute (32 MFMA/wave); __syncthreads(); }
// out = sum_nh relu(A @ W1[:,nh*256:+256] + b1) @ W2[nh*256:+256,:]
// LDS: Aslab 128x64 (16 KB) + Bs 256x64 (32 KB) + Hs 128x256 (64 KB) = 112 KB.
// k-side blocks also cast their 128 val rows into kvB cols 256..511 (tail),
// replacing the old prep kv pass.

constexpr int MLP_QT = T_PAD / 128;       // 254
constexpr int MLP_KT = S_K / 128;         // 132
constexpr int MLP_NB = MLP_QT + MLP_KT;   // 386

__global__ __launch_bounds__(512, 2) void mlp_fused(
    const float* __restrict__ Aq, const float* __restrict__ Ak,
    const float* __restrict__ val_in,
    const __hip_bfloat16* __restrict__ W1q, const __hip_bfloat16* __restrict__ W1k,
    const __hip_bfloat16* __restrict__ W2q, const __hip_bfloat16* __restrict__ W2k,
    const float* __restrict__ b1q, const float* __restrict__ b1k,
    const float* __restrict__ b2q, const float* __restrict__ b2k,
    __hip_bfloat16* __restrict__ Cq, __hip_bfloat16* __restrict__ Ck,
    float scaleq, int qtiles) {
    __shared__ __align__(16) __hip_bfloat16 Aslab[128 * 64];   // 16 KB
    __shared__ __align__(16) __hip_bfloat16 Bs[256 * 64];      // 32 KB
    __shared__ __align__(16) __hip_bfloat16 Hs[128 * 256];     // 64 KB

    const int b = blockIdx.x;
    const bool isq = b < qtiles;
    const float* A  = isq ? Aq : Ak;
    const __hip_bfloat16* W1 = isq ? W1q : W1k;
    const __hip_bfloat16* W2 = isq ? W2q : W2k;
    const float* b1 = isq ? b1q : b1k;
    const float* b2 = isq ? b2q : b2k;
    __hip_bfloat16* C = isq ? Cq : Ck;
    const int ldc = isq ? E_DIM : 512;
    const float scale = isq ? scaleq : 1.0f;
    const int mrow0 = (isq ? b : b - qtiles) * 128;
    const int rowlim = isq ? T_Q : S_K;

    const int tid = threadIdx.x;
    const int w = tid >> 6, l = tid & 63;
    const int lm = l & 15, lq = l >> 4;
    const int wm = w >> 2;                    // M-half: rows wm*64..wm*64+63
    const int wn4 = w & 3;                    // N-quarter: cols wn4*64..+63
    const int srow8 = l >> 3;                 // 0..7
    const int u8 = l & 7;
    const int scolB = (u8 ^ srow8) << 3;      // pre-swizzled source col for DMA

    f32x4 acc2[4][4] = {};

#pragma unroll 1
    for (int nh = 0; nh < 2; ++nh) {
        // ---- phase 1: hidHalf = relu(A @ W1[:, nh*256:+256] + b1half) ----
        f32x4 acc[4][4] = {};
#pragma unroll 1
        for (int st = 0; st < 4; ++st) {
            const int k0 = st * 64;
            // A slab: 128 rows x 64 k, fp32 -> bf16, swizzled ds_write
#pragma unroll
            for (int c = 0; c < 2; ++c) {
                int idx = tid + c * 512;      // 0..1023
                int r = idx >> 3;             // 0..127
                int u = idx & 7;              // unit 0..7
                int gr = mrow0 + r;
                float4 f0 = make_float4(0.f, 0.f, 0.f, 0.f);
                float4 f1 = make_float4(0.f, 0.f, 0.f, 0.f);
                if (gr < rowlim) {
                    const float* ap = A + (size_t)gr * 256 + k0 + u * 8;
                    f0 = *(const float4*)ap;
                    f1 = *(const float4*)(ap + 4);
                }
                union { bf16x8 v; __hip_bfloat16 bb[8]; } cv;
                cv.bb[0] = __float2bfloat16(f0.x); cv.bb[1] = __float2bfloat16(f0.y);
                cv.bb[2] = __float2bfloat16(f0.z); cv.bb[3] = __float2bfloat16(f0.w);
                cv.bb[4] = __float2bfloat16(f1.x); cv.bb[5] = __float2bfloat16(f1.y);
                cv.bb[6] = __float2bfloat16(f1.z); cv.bb[7] = __float2bfloat16(f1.w);
                int pu = u ^ (r & 7);
                *(bf16x8*)(Aslab + r * 64 + pu * 8) = cv.v;
            }
            // B slab: W1 rows nh*256..+255, k cols k0..k0+63 (async DMA)
#pragma unroll
            for (int c = 0; c < 4; ++c) {
                int r = w * 32 + c * 8 + srow8;
                async16(W1 + (size_t)(nh * 256 + r) * 256 + k0 + scolB,
                        Bs + (w * 32 + c * 8) * 64);
            }
            __syncthreads();
#pragma unroll
            for (int ks = 0; ks < 2; ++ks) {
                bf16x8 af[4], bfr[4];
#pragma unroll
                for (int mi = 0; mi < 4; ++mi) {
                    int row = wm * 64 + mi * 16 + lm;
                    int pu = (ks * 4 + lq) ^ (row & 7);
                    af[mi] = *(const bf16x8*)(Aslab + row * 64 + pu * 8);
                }
#pragma unroll
                for (int ni = 0; ni < 4; ++ni) {
                    int brow = wn4 * 64 + ni * 16 + lm;
                    int pu = (ks * 4 + lq) ^ (brow & 7);
                    bfr[ni] = *(const bf16x8*)(Bs + brow * 64 + pu * 8);
                }
#pragma unroll
                for (int mi = 0; mi < 4; ++mi)
#pragma unroll
                    for (int ni = 0; ni < 4; ++ni)
                        acc[mi][ni] = __builtin_amdgcn_mfma_f32_16x16x32_bf16(
                            af[mi], bfr[ni], acc[mi][ni], 0, 0, 0);
            }
            __syncthreads();
        }

        // phase-1 epilogue: bias + relu + cvt -> Hs (128x256, swizzled)
#pragma unroll
        for (int ni = 0; ni < 4; ++ni) {
            int col = wn4 * 64 + ni * 16 + lm;          // 0..255
            float bv = b1[nh * 256 + col];
            int un = col >> 3, el = col & 7;            // un 0..31
#pragma unroll
            for (int mi = 0; mi < 4; ++mi) {
#pragma unroll
                for (int r = 0; r < 4; ++r) {
                    int row = wm * 64 + mi * 16 + lq * 4 + r;   // 0..127
                    float vv = fmaxf(acc[mi][ni][r] + bv, 0.f);
                    int pu = (un & 24) | ((un & 7) ^ (row & 7));
                    Hs[row * 256 + pu * 8 + el] = __float2bfloat16(vv);
                }
            }
        }

        // ---- phase 2 partial: acc2 += hidHalf @ W2[nh*256:+256, :] ----
#pragma unroll 1
        for (int st = 0; st < 4; ++st) {
            const int k0 = st * 64;
#pragma unroll
            for (int c = 0; c < 4; ++c) {
                int r = w * 32 + c * 8 + srow8;         // out col 0..255
                async16(W2 + (size_t)r * 512 + nh * 256 + k0 + scolB,
                        Bs + (w * 32 + c * 8) * 64);
            }
            __syncthreads();     // drains Hs ds_writes (st==0) + Bs DMA
#pragma unroll
            for (int ks = 0; ks < 2; ++ks) {
                bf16x8 af[4], bfr[4];
#pragma unroll
                for (int mi = 0; mi < 4; ++mi) {
                    int row = wm * 64 + mi * 16 + lm;
                    int un = st * 8 + ks * 4 + lq;      // 0..31
                    int pu = (un & 24) | ((un & 7) ^ (row & 7));
                    af[mi] = *(const bf16x8*)(Hs + row * 256 + pu * 8);
                }
#pragma unroll
                for (int ni = 0; ni < 4; ++ni) {
                    int brow = wn4 * 64 + ni * 16 + lm;
                    int pu = (ks * 4 + lq) ^ (brow & 7);
                    bfr[ni] = *(const bf16x8*)(Bs + brow * 64 + pu * 8);
                }
#pragma unroll
                for (int mi = 0; mi < 4; ++mi)
#pragma unroll
                    for (int ni = 0; ni < 4; ++ni)
                        acc2[mi][ni] = __builtin_amdgcn_mfma_f32_16x16x32_bf16(
                            af[mi], bfr[ni], acc2[mi][ni], 0, 0, 0);
            }
            __syncthreads();
        }
    }

    // final epilogue
#pragma unroll
    for (int ni = 0; ni < 4; ++ni) {
        int col = wn4 * 64 + ni * 16 + lm;
        float bv = b2[col];
#pragma unroll
        for (int mi = 0; mi < 4; ++mi) {
            size_t rowb = (size_t)mrow0 + wm * 64 + mi * 16 + lq * 4;
#pragma unroll
            for (int r = 0; r < 4; ++r) {
                float vv = (acc2[mi][ni][r] + bv) * scale;
                C[(rowb + r) * ldc + col] = __float2bfloat16(vv);
            }
        }
    }

    // k-side tail: cast this block's 128 val rows into kvB cols 256..511
    if (!isq) {
#pragma unroll
        for (int i = 0; i < 16; ++i) {
            int idx = tid + i * 512;          // 0..8191
            int r = idx >> 6;                 // 0..127
            int c4 = idx & 63;                // float4 index within row
            int gr = mrow0 + r;
            float4 f = *(const float4*)(val_in + (size_t)gr * 256 + c4 * 4);
            union { ushort4 u4; __hip_bfloat16 bb[4]; } cv;
            cv.bb[0] = __float2bfloat16(f.x);
            cv.bb[1] = __float2bfloat16(f.y);
            cv.bb[2] = __float2bfloat16(f.z);
            cv.bb[3] = __float2bfloat16(f.w);
            *(ushort4*)(Ck + (size_t)gr * 512 + 256 + c4 * 4) = cv.u4;
        }
    }
}

// ---------------------------------------------------------------------------
// Attention: one wave per query, TWO points per step (one per half-wave).
// 4 pair-buffers deep register prefetch (8 points lookahead).
// Defer-max skips the rescale when no head's pair-max beats the running max.
// Persistent grid: 2026 blocks fully resident.

#define PREFP(KB, VB, C)                                                     \
    {                                                                        \
        int f_ = __shfl(myf, (C) + half);                                    \
        const __hip_bfloat16* p_ = kv + ((size_t)f_ << 9) + (sub << 3);      \
        KB = *(const ushort8v*)p_;                                           \
        VB = *(const ushort8v*)(p_ + 256);                                   \
    }

#define PROCP(KB, VB, C)                                                     \
    {                                                                        \
        float wv = 0.f;                                                      \
        _Pragma("unroll") for (int i = 0; i < 8; ++i)                        \
            wv = fmaf(qf[i], b2f(KB[i]), wv);                                \
        wv += __shfl_xor(wv, 1);                                             \
        wv += __shfl_xor(wv, 2);                                             \
        float sc = ((C) + half < L) ? wv : -1e30f;                           \
        float so = __shfl_xor(sc, 32);                                       \
        float pm = fmaxf(sc, so);                                            \
        if (__all(pm <= m)) {                                                \
            float p = __expf(sc - m);                                        \
            s += p;                                                          \
            _Pragma("unroll") for (int i = 0; i < 8; ++i)                    \
                a[i] = fmaf(p, b2f(VB[i]), a[i]);                            \
        } else {                                                             \
            float mn = fmaxf(m, pm);                                         \
            float al = __expf(m - mn);                                       \
            float p  = __expf(sc - mn);                                      \
            m = mn;                                                          \
            s = fmaf(s, al, p);                                              \
            _Pragma("unroll") for (int i = 0; i < 8; ++i)                    \
                a[i] = fmaf(p, b2f(VB[i]), a[i] * al);                       \
        }                                                                    \
    }

#define STEPP(KB, VB, J)                                                     \
    if (c + (J) < L) {                                                       \
        PROCP(KB, VB, c + (J));                                              \
        if (c + (J) + 8 < L) PREFP(KB, VB, c + (J) + 8);                     \
    }

constexpr int ATTN_BLOCKS = 2026;   // fully resident

__global__ __launch_bounds__(256) void attn_kernel(
    const __hip_bfloat16* __restrict__ q,
    const __hip_bfloat16* __restrict__ kv,
    const int* __restrict__ rf,
    const int* __restrict__ starts,
    const int* __restrict__ lens,
    float* __restrict__ out) {
    const int wid = threadIdx.x >> 6;
    const int l = threadIdx.x & 63;
    const int sub = l & 31, half = l >> 5;
    const int tstride = gridDim.x * 4;

    for (int t = blockIdx.x * 4 + wid; t < T_Q; t += tstride) {
        int su = __builtin_amdgcn_readfirstlane(starts[t]);
        int L  = __builtin_amdgcn_readfirstlane(lens[t]);

        int li = l < L - 1 ? l : L - 1;   // clamp so any shfl source is valid
        int myf = rf[su + li];

        ushort8v qu = *(const ushort8v*)(q + (size_t)t * 256 + sub * 8);
        float qf[8];
#pragma unroll
        for (int i = 0; i < 8; ++i) qf[i] = b2f(qu[i]);

        float m = -INFINITY, s = 0.f;
        float a[8] = {0.f, 0.f, 0.f, 0.f, 0.f, 0.f, 0.f, 0.f};

        ushort8v k0 = {}, v0 = {}, k1 = {}, v1 = {};
        ushort8v k2 = {}, v2 = {}, k3 = {}, v3 = {};
        PREFP(k0, v0, 0);
        if (L > 2) PREFP(k1, v1, 2);
        if (L > 4) PREFP(k2, v2, 4);
        if (L > 6) PREFP(k3, v3, 6);

        for (int c = 0; c < L; c += 8) {
            STEPP(k0, v0, 0)
            STEPP(k1, v1, 2)
            STEPP(k2, v2, 4)
            STEPP(k3, v3, 6)
        }

        // merge half-wave partials (both halves end with identical m)
        float st = s + __shfl_xor(s, 32);
#pragma unroll
        for (int i = 0; i < 8; ++i) a[i] += __shfl_xor(a[i], 32);

        // v-half lanes write: lane 32+x owns out dims x*8..x*8+7
        if (half) {
            float inv = 1.f / st;
            float* op = out + (size_t)t * 256 + sub * 8;
            float4 o0, o1;
            o0.x = a[0] * inv; o0.y = a[1] * inv; o0.z = a[2] * inv; o0.w = a[3] * inv;
            o1.x = a[4] * inv; o1.y = a[5] * inv; o1.z = a[6] * inv; o1.w = a[7] * inv;
            *(float4*)op = o0;
            *(float4*)(op + 4) = o1;
        }
    }
}

// ---------------------------------------------------------------------------
extern "C" void kernel_launch(void* const* d_in, const int* in_sizes, int n_in,
                              void* d_out, int out_size, void* d_ws, size_t ws_size,
                              hipStream_t stream) {
    const float* q_in   = (const float*)d_in[0];
    const float* key_in = (const float*)d_in[1];
    const float* val_in = (const float*)d_in[2];
    const float* q_w1   = (const float*)d_in[3];
    const float* q_b1   = (const float*)d_in[4];
    const float* q_w2   = (const float*)d_in[5];
    const float* q_b2   = (const float*)d_in[6];
    const float* k_w1   = (const float*)d_in[7];
    const float* k_b1   = (const float*)d_in[8];
    const float* k_w2   = (const float*)d_in[9];
    const float* k_b2   = (const float*)d_in[10];
    const int* ranks_feat = (const int*)d_in[11];
    const int* starts     = (const int*)d_in[13];
    const int* lens       = (const int*)d_in[14];
    float* out = (float*)d_out;

    char* ws = (char*)d_ws;
    size_t off = 0;
    auto alloc = [&](size_t bytes) {
        char* p = ws + off;
        off += (bytes + 255) & ~(size_t)255;
        return p;
    };
    __hip_bfloat16* qMl  = (__hip_bfloat16*)alloc((size_t)T_PAD * E_DIM * 2);
    __hip_bfloat16* kvB  = (__hip_bfloat16*)alloc((size_t)S_K * 512 * 2);
    __hip_bfloat16* w1qT = (__hip_bfloat16*)alloc((size_t)HID * E_DIM * 2);
    __hip_bfloat16* w2qT = (__hip_bfloat16*)alloc((size_t)E_DIM * HID * 2);
    __hip_bfloat16* w1kT = (__hip_bfloat16*)alloc((size_t)HID * E_DIM * 2);
    __hip_bfloat16* w2kT = (__hip_bfloat16*)alloc((size_t)E_DIM * HID * 2);
    (void)ws_size; (void)n_in; (void)out_size; (void)in_sizes;

    prep<<<128, 256, 0, stream>>>(q_w1, q_w2, k_w1, k_w2,
                                  w1qT, w2qT, w1kT, w2kT);

    const float qscale = 0.17677669529663687f;  // 1/sqrt(32)

    mlp_fused<<<MLP_NB, 512, 0, stream>>>(
        q_in, key_in, val_in, w1qT, w1kT, w2qT, w2kT,
        q_b1, k_b1, q_b2, k_b2, qMl, kvB, qscale, MLP_QT);

    attn_kernel<<<ATTN_BLOCKS, 256, 0, stream>>>(qMl, kvB, ranks_feat, starts, lens, out);
}